// Round 1
// baseline (672.861 us; speedup 1.0000x reference)
//
#include <hip/hip_runtime.h>

// GCN edge predictor, algebraically collapsed:
// the reference is fully linear, so
//   out[g] = sum_{i in g} t_i + c0
//   u_i = x_i . w1c            (w1c = W1 W2 Wf1 Wf2 Wf3 Wo, [64])
//   v   = A_norm u + c1        (c1 = b1 . (W2 Wf1 Wf2 Wf3 Wo))
//   t   = A_norm v + c2        (c2 = b2 . (Wf1 Wf2 Wf3 Wo))
//   c0  = bf1.w2 + bf2.w3 + bf3.wo + bo
// A_norm = D^-1/2 (A + I) D^-1/2 with degrees over dst (incl self loop).

__global__ void collapse_weights_k(
    const float* __restrict__ W1, const float* __restrict__ b1,
    const float* __restrict__ W2, const float* __restrict__ b2,
    const float* __restrict__ Wf1, const float* __restrict__ bf1,
    const float* __restrict__ Wf2, const float* __restrict__ bf2,
    const float* __restrict__ Wf3, const float* __restrict__ bf3,
    const float* __restrict__ Wo, const float* __restrict__ bo,
    float* __restrict__ w1c, float* __restrict__ sc)
{
    __shared__ float wo[10], w3[20], w2[30], w1[50], w2c[60];
    const int t = threadIdx.x;  // 64 threads
    if (t < 10) wo[t] = Wo[t];
    __syncthreads();
    if (t < 20) { float s = 0.f; for (int j = 0; j < 10; ++j) s += Wf3[t*10+j]*wo[j]; w3[t] = s; }
    __syncthreads();
    if (t < 30) { float s = 0.f; for (int j = 0; j < 20; ++j) s += Wf2[t*20+j]*w3[j]; w2[t] = s; }
    __syncthreads();
    if (t < 50) { float s = 0.f; for (int j = 0; j < 30; ++j) s += Wf1[t*30+j]*w2[j]; w1[t] = s; }
    __syncthreads();
    if (t < 60) { float s = 0.f; for (int j = 0; j < 50; ++j) s += W2[t*50+j]*w1[j]; w2c[t] = s; }
    __syncthreads();
    { float s = 0.f; for (int j = 0; j < 60; ++j) s += W1[t*60+j]*w2c[j]; w1c[t] = s; }
    if (t == 0) {
        float c1 = 0.f; for (int j = 0; j < 60; ++j) c1 += b1[j]*w2c[j];
        float c2 = 0.f; for (int j = 0; j < 50; ++j) c2 += b2[j]*w1[j];
        float c0 = bo[0];
        for (int j = 0; j < 30; ++j) c0 += bf1[j]*w2[j];
        for (int j = 0; j < 20; ++j) c0 += bf2[j]*w3[j];
        for (int j = 0; j < 10; ++j) c0 += bf3[j]*wo[j];
        sc[0] = c1; sc[1] = c2; sc[2] = c0;
    }
}

__global__ void fill_deg_k(float* __restrict__ deg, int n) {
    int i = blockIdx.x * blockDim.x + threadIdx.x;
    if (i < n) deg[i] = 1.0f;   // self loop
}

__global__ void degree_k(const int* __restrict__ dst, float* __restrict__ deg, int E) {
    int e = (blockIdx.x * blockDim.x + threadIdx.x) * 4;
    if (e + 3 < E) {
        int4 d4 = *reinterpret_cast<const int4*>(dst + e);
        atomicAdd(&deg[d4.x], 1.0f);
        atomicAdd(&deg[d4.y], 1.0f);
        atomicAdd(&deg[d4.z], 1.0f);
        atomicAdd(&deg[d4.w], 1.0f);
    } else {
        for (int k = e; k < E; ++k) atomicAdd(&deg[dst[k]], 1.0f);
    }
}

// one wave per node: u[i] = x[i,:] . w1c ; also deg -> dinv in place
__global__ void node_u_k(const float* __restrict__ x, const float* __restrict__ w1c,
                         float* __restrict__ degdinv, float* __restrict__ u, int n) {
    int gid = blockIdx.x * blockDim.x + threadIdx.x;
    int node = gid >> 6;
    int lane = threadIdx.x & 63;
    if (node >= n) return;
    float val = x[(size_t)node * 64 + lane] * w1c[lane];
    #pragma unroll
    for (int o = 32; o > 0; o >>= 1) val += __shfl_down(val, o, 64);
    if (lane == 0) {
        u[node] = val;
        degdinv[node] = rsqrtf(degdinv[node]);
    }
}

// dstv[i] = sc[scIdx] + dinv[i]^2 * srcv[i]  (self-loop term + bias const)
// optionally also inits out[g] = c0
__global__ void init_node_k(const float* __restrict__ dinv, const float* __restrict__ srcv,
                            float* __restrict__ dstv, const float* __restrict__ sc,
                            int scIdx, int n, float* __restrict__ out, int G) {
    int i = blockIdx.x * blockDim.x + threadIdx.x;
    if (i < n) {
        float di = dinv[i];
        dstv[i] = sc[scIdx] + di * di * srcv[i];
    }
    if (out != nullptr && i < G) out[i] = sc[2];
}

__global__ void edge_conv_k(const int* __restrict__ srcl, const int* __restrict__ dstl,
                            const float* __restrict__ dinv, const float* __restrict__ uin,
                            float* __restrict__ vout, int E) {
    int e = (blockIdx.x * blockDim.x + threadIdx.x) * 4;
    if (e + 3 < E) {
        int4 s4 = *reinterpret_cast<const int4*>(srcl + e);
        int4 d4 = *reinterpret_cast<const int4*>(dstl + e);
        atomicAdd(&vout[d4.x], dinv[s4.x] * dinv[d4.x] * uin[s4.x]);
        atomicAdd(&vout[d4.y], dinv[s4.y] * dinv[d4.y] * uin[s4.y]);
        atomicAdd(&vout[d4.z], dinv[s4.z] * dinv[d4.z] * uin[s4.z]);
        atomicAdd(&vout[d4.w], dinv[s4.w] * dinv[d4.w] * uin[s4.w]);
    } else {
        for (int k = e; k < E; ++k) {
            int s = srcl[k], d = dstl[k];
            atomicAdd(&vout[d], dinv[s] * dinv[d] * uin[s]);
        }
    }
}

// batch is sorted; each thread handles 4 consecutive nodes, run-compresses
__global__ void pool_k(const float* __restrict__ t, const int* __restrict__ batch,
                       float* __restrict__ out, int n) {
    int base = (blockIdx.x * blockDim.x + threadIdx.x) * 4;
    if (base >= n) return;
    int end = base + 4; if (end > n) end = n;
    int cur = batch[base]; float acc = t[base];
    for (int i = base + 1; i < end; ++i) {
        int b = batch[i];
        if (b == cur) acc += t[i];
        else { atomicAdd(&out[cur], acc); cur = b; acc = t[i]; }
    }
    atomicAdd(&out[cur], acc);
}

extern "C" void kernel_launch(void* const* d_in, const int* in_sizes, int n_in,
                              void* d_out, int out_size, void* d_ws, size_t ws_size,
                              hipStream_t stream)
{
    const float* x    = (const float*)d_in[0];
    const int*   ei   = (const int*)d_in[1];
    const int*   batch= (const int*)d_in[2];
    const float* W1   = (const float*)d_in[3];
    const float* b1   = (const float*)d_in[4];
    const float* W2   = (const float*)d_in[5];
    const float* b2   = (const float*)d_in[6];
    const float* Wf1  = (const float*)d_in[7];
    const float* bf1  = (const float*)d_in[8];
    const float* Wf2  = (const float*)d_in[9];
    const float* bf2  = (const float*)d_in[10];
    const float* Wf3  = (const float*)d_in[11];
    const float* bf3  = (const float*)d_in[12];
    const float* Wo   = (const float*)d_in[13];
    const float* bo   = (const float*)d_in[14];
    float* out = (float*)d_out;

    const int n = in_sizes[0] / 64;
    const int E = in_sizes[1] / 2;
    const int G = out_size;
    const int* src = ei;
    const int* dst = ei + E;

    float* ws  = (float*)d_ws;
    float* w1c = ws;          // 64
    float* sc  = ws + 64;     // 3 (c1, c2, c0)
    float* deg = ws + 128;    // n  (becomes dinv in place)
    float* u   = deg + n;     // n
    float* v   = u + n;       // n
    float* t   = v + n;       // n

    const int B = 256;
    const int Ne4 = (E + 3) / 4;
    const int egrid = (Ne4 + B - 1) / B;
    const int ngrid = (n + B - 1) / B;

    hipLaunchKernelGGL(collapse_weights_k, dim3(1), dim3(64), 0, stream,
                       W1, b1, W2, b2, Wf1, bf1, Wf2, bf2, Wf3, bf3, Wo, bo, w1c, sc);
    hipLaunchKernelGGL(fill_deg_k, dim3(ngrid), dim3(B), 0, stream, deg, n);
    hipLaunchKernelGGL(degree_k, dim3(egrid), dim3(B), 0, stream, dst, deg, E);
    hipLaunchKernelGGL(node_u_k, dim3((n * 64 + B - 1) / B), dim3(B), 0, stream,
                       x, w1c, deg, u, n);
    hipLaunchKernelGGL(init_node_k, dim3(ngrid), dim3(B), 0, stream,
                       deg, u, v, sc, 0, n, out, G);
    hipLaunchKernelGGL(edge_conv_k, dim3(egrid), dim3(B), 0, stream,
                       src, dst, deg, u, v, E);
    hipLaunchKernelGGL(init_node_k, dim3(ngrid), dim3(B), 0, stream,
                       deg, v, t, sc, 1, n, (float*)nullptr, G);
    hipLaunchKernelGGL(edge_conv_k, dim3(egrid), dim3(B), 0, stream,
                       src, dst, deg, v, t, E);
    hipLaunchKernelGGL(pool_k, dim3(((n + 3) / 4 + B - 1) / B, 1, 1), dim3(B), 0, stream,
                       t, batch, out, n);
}

// Round 2
// 285.526 us; speedup vs baseline: 2.3566x; 2.3566x over previous
//
#include <hip/hip_runtime.h>

// GCN edge predictor, collapsed to scalar-per-node linear algebra (R1), now
// with atomic-free aggregation (R2): bucket edges by dst>>8 once, then all
// scatter-adds happen in LDS (one block owns one 256-node bucket).
//
//   u_i = x_i . w1c
//   v   = A u + c1 ;  t = A v + c2 ;  out[g] = sum_{i in g} t_i + c0
//   A = D^-1/2 (Adj + I) D^-1/2
// Per edge (s,d): contribution dinv[s]*dinv[d]*h[s] = dinv[d] * (dinv[s]*h[s])
// -> gather w[s] = dinv[s]*h[s], LDS-accumulate per d, multiply dinv[d] in the
// epilogue. Self loop handled in epilogue: + dinv[d]^2 * h[d].

#define RSHIFT 8
#define RNODES 256           // nodes per bucket (1 block per bucket)
#define MAXNB  512           // max buckets (n <= 131072; src fits 17 bits)
#define BINBLOCKS 128        // blocks for count/scatter passes

__global__ void collapse_weights_k(
    const float* __restrict__ W1, const float* __restrict__ b1,
    const float* __restrict__ W2, const float* __restrict__ b2,
    const float* __restrict__ Wf1, const float* __restrict__ bf1,
    const float* __restrict__ Wf2, const float* __restrict__ bf2,
    const float* __restrict__ Wf3, const float* __restrict__ bf3,
    const float* __restrict__ Wo, const float* __restrict__ bo,
    float* __restrict__ w1c, float* __restrict__ sc,
    int* __restrict__ cnt, int nb)
{
    __shared__ float wo[10], w3[20], w2[30], w1[50], w2c[60];
    const int t = threadIdx.x;  // 64 threads
    for (int b = t; b < nb; b += 64) cnt[b] = 0;   // zero bucket counters
    if (t < 10) wo[t] = Wo[t];
    __syncthreads();
    if (t < 20) { float s = 0.f; for (int j = 0; j < 10; ++j) s += Wf3[t*10+j]*wo[j]; w3[t] = s; }
    __syncthreads();
    if (t < 30) { float s = 0.f; for (int j = 0; j < 20; ++j) s += Wf2[t*20+j]*w3[j]; w2[t] = s; }
    __syncthreads();
    if (t < 50) { float s = 0.f; for (int j = 0; j < 30; ++j) s += Wf1[t*30+j]*w2[j]; w1[t] = s; }
    __syncthreads();
    if (t < 60) { float s = 0.f; for (int j = 0; j < 50; ++j) s += W2[t*50+j]*w1[j]; w2c[t] = s; }
    __syncthreads();
    { float s = 0.f; for (int j = 0; j < 60; ++j) s += W1[t*60+j]*w2c[j]; w1c[t] = s; }
    if (t == 0) {
        float c1 = 0.f; for (int j = 0; j < 60; ++j) c1 += b1[j]*w2c[j];
        float c2 = 0.f; for (int j = 0; j < 50; ++j) c2 += b2[j]*w1[j];
        float c0 = bo[0];
        for (int j = 0; j < 30; ++j) c0 += bf1[j]*w2[j];
        for (int j = 0; j < 20; ++j) c0 += bf2[j]*w3[j];
        for (int j = 0; j < 10; ++j) c0 += bf3[j]*wo[j];
        sc[0] = c1; sc[1] = c2; sc[2] = c0;
    }
}

// one wave per node: u[i] = x[i,:] . w1c
__global__ void node_u_k(const float* __restrict__ x, const float* __restrict__ w1c,
                         float* __restrict__ u, int n) {
    int gid = blockIdx.x * blockDim.x + threadIdx.x;
    int node = gid >> 6;
    int lane = threadIdx.x & 63;
    if (node >= n) return;
    float val = x[(size_t)node * 64 + lane] * w1c[lane];
    #pragma unroll
    for (int o = 32; o > 0; o >>= 1) val += __shfl_down(val, o, 64);
    if (lane == 0) u[node] = val;
}

// count edges per bucket: per-block LDS histogram, one global atomic per bucket
__global__ void bin_count_k(const int* __restrict__ dst, int E, int chunk,
                            int nb, int* __restrict__ cnt) {
    __shared__ int hist[MAXNB];
    int e0 = blockIdx.x * chunk;
    int e1 = e0 + chunk; if (e1 > E) e1 = E;
    if (e0 >= E) return;
    for (int b = threadIdx.x; b < nb; b += blockDim.x) hist[b] = 0;
    __syncthreads();
    for (int i = e0 + threadIdx.x * 4; i + 3 < e1; i += blockDim.x * 4) {
        int4 d = *reinterpret_cast<const int4*>(dst + i);
        atomicAdd(&hist[d.x >> RSHIFT], 1);
        atomicAdd(&hist[d.y >> RSHIFT], 1);
        atomicAdd(&hist[d.z >> RSHIFT], 1);
        atomicAdd(&hist[d.w >> RSHIFT], 1);
    }
    int rem = (e1 - e0) & 3;
    if ((int)threadIdx.x < rem) atomicAdd(&hist[dst[e1 - rem + threadIdx.x] >> RSHIFT], 1);
    __syncthreads();
    for (int b = threadIdx.x; b < nb; b += blockDim.x)
        if (hist[b]) atomicAdd(&cnt[b], hist[b]);
}

// exclusive scan over buckets (tiny) + init cursors + init out[g] = c0
__global__ void scan_init_k(const int* __restrict__ cnt, int nb,
                            int* __restrict__ base, int* __restrict__ cursor,
                            const float* __restrict__ sc, float* __restrict__ out, int G) {
    int t = threadIdx.x;
    if (t < G) out[t] = sc[2];
    if (t == 0) {
        int acc = 0;
        for (int b = 0; b < nb; ++b) { base[b] = acc; acc += cnt[b]; }
        base[nb] = acc;
    }
    __syncthreads();
    for (int b = t; b < nb; b += blockDim.x) cursor[b] = base[b];
}

// scatter packed edges into bucket-contiguous layout
__global__ void bin_scatter_k(const int* __restrict__ src, const int* __restrict__ dst,
                              int E, int chunk, int nb,
                              int* __restrict__ cursor, unsigned int* __restrict__ binned) {
    __shared__ int hist[MAXNB];
    int e0 = blockIdx.x * chunk;
    int e1 = e0 + chunk; if (e1 > E) e1 = E;
    if (e0 >= E) return;
    for (int b = threadIdx.x; b < nb; b += blockDim.x) hist[b] = 0;
    __syncthreads();
    for (int i = e0 + threadIdx.x * 4; i + 3 < e1; i += blockDim.x * 4) {
        int4 d = *reinterpret_cast<const int4*>(dst + i);
        atomicAdd(&hist[d.x >> RSHIFT], 1);
        atomicAdd(&hist[d.y >> RSHIFT], 1);
        atomicAdd(&hist[d.z >> RSHIFT], 1);
        atomicAdd(&hist[d.w >> RSHIFT], 1);
    }
    int rem = (e1 - e0) & 3;
    if ((int)threadIdx.x < rem) atomicAdd(&hist[dst[e1 - rem + threadIdx.x] >> RSHIFT], 1);
    __syncthreads();
    // reserve global space per bucket; hist becomes this block's running cursor
    for (int b = threadIdx.x; b < nb; b += blockDim.x) {
        int c = hist[b];
        hist[b] = c ? atomicAdd(&cursor[b], c) : 0;
    }
    __syncthreads();
    for (int i = e0 + threadIdx.x * 4; i + 3 < e1; i += blockDim.x * 4) {
        int4 s4 = *reinterpret_cast<const int4*>(src + i);
        int4 d4 = *reinterpret_cast<const int4*>(dst + i);
        int p;
        p = atomicAdd(&hist[d4.x >> RSHIFT], 1);
        binned[p] = (unsigned)s4.x | ((unsigned)(d4.x & (RNODES-1)) << 17);
        p = atomicAdd(&hist[d4.y >> RSHIFT], 1);
        binned[p] = (unsigned)s4.y | ((unsigned)(d4.y & (RNODES-1)) << 17);
        p = atomicAdd(&hist[d4.z >> RSHIFT], 1);
        binned[p] = (unsigned)s4.z | ((unsigned)(d4.z & (RNODES-1)) << 17);
        p = atomicAdd(&hist[d4.w >> RSHIFT], 1);
        binned[p] = (unsigned)s4.w | ((unsigned)(d4.w & (RNODES-1)) << 17);
    }
    if ((int)threadIdx.x < rem) {
        int i = e1 - rem + threadIdx.x;
        int s = src[i], d = dst[i];
        int p = atomicAdd(&hist[d >> RSHIFT], 1);
        binned[p] = (unsigned)s | ((unsigned)(d & (RNODES-1)) << 17);
    }
}

// per-bucket in-degree count -> dinv = rsqrt(deg+1); also w = dinv * u
__global__ void degree_k(const unsigned int* __restrict__ binned, const int* __restrict__ base,
                         const float* __restrict__ u,
                         float* __restrict__ dinv, float* __restrict__ w, int n) {
    __shared__ int cnt[RNODES];
    int tid = threadIdx.x, b = blockIdx.x;
    cnt[tid] = 0;
    __syncthreads();
    int s0 = base[b], s1 = base[b + 1];
    for (int i = s0 + tid; i < s1; i += RNODES)
        atomicAdd(&cnt[binned[i] >> 17], 1);
    __syncthreads();
    int g = (b << RSHIFT) + tid;
    if (g < n) {
        float d = rsqrtf((float)(cnt[tid] + 1));
        dinv[g] = d;
        w[g] = d * u[g];
    }
}

// middle conv: v = c1 + dinv*(LDS-sum of w[src]) + dinv^2*u ; wb = dinv*v
__global__ void conv_mid_k(const unsigned int* __restrict__ binned, const int* __restrict__ base,
                           const float* __restrict__ w, const float* __restrict__ dinv,
                           const float* __restrict__ u, const float* __restrict__ sc,
                           float* __restrict__ v, float* __restrict__ wb, int n) {
    __shared__ float acc[RNODES];
    int tid = threadIdx.x, b = blockIdx.x;
    acc[tid] = 0.f;
    __syncthreads();
    int s0 = base[b], s1 = base[b + 1];
    for (int i = s0 + tid; i < s1; i += RNODES) {
        unsigned p = binned[i];
        atomicAdd(&acc[p >> 17], w[p & 0x1FFFF]);
    }
    __syncthreads();
    int g = (b << RSHIFT) + tid;
    if (g < n) {
        float di = dinv[g];
        float val = sc[0] + di * acc[tid] + di * di * u[g];
        v[g] = val;
        wb[g] = di * val;
    }
}

// final conv fused with global_add_pool: t = c2 + dinv*sum + dinv^2*v,
// then segmented-reduce t by (sorted) batch id within the block.
__global__ void conv_final_k(const unsigned int* __restrict__ binned, const int* __restrict__ base,
                             const float* __restrict__ wb, const float* __restrict__ dinv,
                             const float* __restrict__ v, const float* __restrict__ sc,
                             const int* __restrict__ batch, float* __restrict__ out, int n) {
    __shared__ float acc[RNODES];
    __shared__ float tbuf[RNODES];
    __shared__ int gbuf[RNODES];
    int tid = threadIdx.x, b = blockIdx.x;
    acc[tid] = 0.f;
    __syncthreads();
    int s0 = base[b], s1 = base[b + 1];
    for (int i = s0 + tid; i < s1; i += RNODES) {
        unsigned p = binned[i];
        atomicAdd(&acc[p >> 17], wb[p & 0x1FFFF]);
    }
    __syncthreads();
    int g = (b << RSHIFT) + tid;
    float tval = 0.f; int gid = -1;
    if (g < n) {
        float di = dinv[g];
        tval = sc[1] + di * acc[tid] + di * di * v[g];
        gid = batch[g];
    }
    tbuf[tid] = tval; gbuf[tid] = gid;
    __syncthreads();
    bool head = (g < n) && (tid == 0 || gbuf[tid - 1] != gid);
    if (head) {
        float s = 0.f;
        int i = tid;
        while (i < RNODES && gbuf[i] == gid) { s += tbuf[i]; ++i; }
        atomicAdd(&out[gid], s);
    }
}

extern "C" void kernel_launch(void* const* d_in, const int* in_sizes, int n_in,
                              void* d_out, int out_size, void* d_ws, size_t ws_size,
                              hipStream_t stream)
{
    const float* x    = (const float*)d_in[0];
    const int*   ei   = (const int*)d_in[1];
    const int*   batch= (const int*)d_in[2];
    const float* W1   = (const float*)d_in[3];
    const float* b1   = (const float*)d_in[4];
    const float* W2   = (const float*)d_in[5];
    const float* b2   = (const float*)d_in[6];
    const float* Wf1  = (const float*)d_in[7];
    const float* bf1  = (const float*)d_in[8];
    const float* Wf2  = (const float*)d_in[9];
    const float* bf2  = (const float*)d_in[10];
    const float* Wf3  = (const float*)d_in[11];
    const float* bf3  = (const float*)d_in[12];
    const float* Wo   = (const float*)d_in[13];
    const float* bo   = (const float*)d_in[14];
    float* out = (float*)d_out;

    const int n = in_sizes[0] / 64;
    const int E = in_sizes[1] / 2;
    const int G = out_size;
    const int* src = ei;
    const int* dst = ei + E;
    const int nb = (n + RNODES - 1) >> RSHIFT;

    float* ws_f = (float*)d_ws;
    int*   ws_i = (int*)d_ws;
    float* w1c   = ws_f;                 // 64
    float* sc    = ws_f + 64;            // 3
    int*   cnt   = ws_i + 128;           // nb
    int*   basep = ws_i + 768;           // nb+1
    int*   cursor= ws_i + 1536;          // nb
    float* u     = ws_f + 2048;          // n
    float* dinv  = u + n;                // n
    float* w     = dinv + n;             // n  (dinv*u)
    float* v     = w + n;                // n
    float* wb    = v + n;                // n  (dinv*v)
    unsigned int* binned = (unsigned int*)(wb + n);  // E

    const int B = 256;
    int chunk = (E + BINBLOCKS - 1) / BINBLOCKS;
    chunk = (chunk + 3) & ~3;

    hipLaunchKernelGGL(collapse_weights_k, dim3(1), dim3(64), 0, stream,
                       W1, b1, W2, b2, Wf1, bf1, Wf2, bf2, Wf3, bf3, Wo, bo,
                       w1c, sc, cnt, nb);
    hipLaunchKernelGGL(node_u_k, dim3((n * 64 + B - 1) / B), dim3(B), 0, stream,
                       x, w1c, u, n);
    hipLaunchKernelGGL(bin_count_k, dim3(BINBLOCKS), dim3(B), 0, stream,
                       dst, E, chunk, nb, cnt);
    hipLaunchKernelGGL(scan_init_k, dim3(1), dim3(B), 0, stream,
                       cnt, nb, basep, cursor, sc, out, G);
    hipLaunchKernelGGL(bin_scatter_k, dim3(BINBLOCKS), dim3(B), 0, stream,
                       src, dst, E, chunk, nb, cursor, binned);
    hipLaunchKernelGGL(degree_k, dim3(nb), dim3(RNODES), 0, stream,
                       binned, basep, u, dinv, w, n);
    hipLaunchKernelGGL(conv_mid_k, dim3(nb), dim3(RNODES), 0, stream,
                       binned, basep, w, dinv, u, sc, v, wb, n);
    hipLaunchKernelGGL(conv_final_k, dim3(nb), dim3(RNODES), 0, stream,
                       binned, basep, wb, dinv, v, sc, batch, out, n);
}

// Round 3
// 221.950 us; speedup vs baseline: 3.0316x; 1.2864x over previous
//
#include <hip/hip_runtime.h>

// GCN edge predictor, collapsed to scalar-per-node linear algebra:
//   u_i = x_i . w1c
//   v   = A u + c1 ;  t = A v + c2 ;  out[g] = sum_{i in g} t_i + c0
//   A = D^-1/2 (Adj + I) D^-1/2
// Edge (s,d) contributes dinv[d] * (dinv[s]*h[s]) -> gather w[s]=dinv[s]*h[s],
// LDS-accumulate per d (edges bucketed by d>>7), dinv[d] in epilogue.
// R3: latency-bound fixes — uint4 edge streams (4 gathers in flight),
// parallel LDS scan, finer buckets (128 nodes -> 782 blocks), wide bin passes.

#define RSHIFT 7
#define RNODES 128           // nodes per bucket
#define MAXNB  1024          // max buckets (n <= 131072; src fits 17 bits)
#define BINBLOCKS 192
#define BINTHREADS 512

__global__ void collapse_weights_k(
    const float* __restrict__ W1, const float* __restrict__ b1,
    const float* __restrict__ W2, const float* __restrict__ b2,
    const float* __restrict__ Wf1, const float* __restrict__ bf1,
    const float* __restrict__ Wf2, const float* __restrict__ bf2,
    const float* __restrict__ Wf3, const float* __restrict__ bf3,
    const float* __restrict__ Wo, const float* __restrict__ bo,
    float* __restrict__ w1c, float* __restrict__ sc,
    int* __restrict__ cnt, int nb)
{
    __shared__ float wo[10], w3[20], w2[30], w1[50], w2c[60];
    const int t = threadIdx.x;  // 64 threads
    for (int b = t; b < nb; b += 64) cnt[b] = 0;   // zero bucket counters
    if (t < 10) wo[t] = Wo[t];
    __syncthreads();
    if (t < 20) { float s = 0.f; for (int j = 0; j < 10; ++j) s += Wf3[t*10+j]*wo[j]; w3[t] = s; }
    __syncthreads();
    if (t < 30) { float s = 0.f; for (int j = 0; j < 20; ++j) s += Wf2[t*20+j]*w3[j]; w2[t] = s; }
    __syncthreads();
    if (t < 50) { float s = 0.f; for (int j = 0; j < 30; ++j) s += Wf1[t*30+j]*w2[j]; w1[t] = s; }
    __syncthreads();
    if (t < 60) { float s = 0.f; for (int j = 0; j < 50; ++j) s += W2[t*50+j]*w1[j]; w2c[t] = s; }
    __syncthreads();
    { float s = 0.f; for (int j = 0; j < 60; ++j) s += W1[t*60+j]*w2c[j]; w1c[t] = s; }
    if (t == 0) {
        float c1 = 0.f; for (int j = 0; j < 60; ++j) c1 += b1[j]*w2c[j];
        float c2 = 0.f; for (int j = 0; j < 50; ++j) c2 += b2[j]*w1[j];
        float c0 = bo[0];
        for (int j = 0; j < 30; ++j) c0 += bf1[j]*w2[j];
        for (int j = 0; j < 20; ++j) c0 += bf2[j]*w3[j];
        for (int j = 0; j < 10; ++j) c0 += bf3[j]*wo[j];
        sc[0] = c1; sc[1] = c2; sc[2] = c0;
    }
}

// 4 nodes per wave, float4 per 16-lane group: u[i] = x[i,:] . w1c
__global__ void node_u_k(const float* __restrict__ x, const float* __restrict__ w1c,
                         float* __restrict__ u, int n) {
    int tid = blockIdx.x * blockDim.x + threadIdx.x;
    int wave = tid >> 6;
    int lane = threadIdx.x & 63;
    int node = wave * 4 + (lane >> 4);
    int sub = lane & 15;
    if (node >= n) return;
    float4 xv = *reinterpret_cast<const float4*>(x + (size_t)node * 64 + sub * 4);
    float4 wv = *reinterpret_cast<const float4*>(w1c + sub * 4);
    float val = xv.x * wv.x + xv.y * wv.y + xv.z * wv.z + xv.w * wv.w;
    val += __shfl_down(val, 8, 16);
    val += __shfl_down(val, 4, 16);
    val += __shfl_down(val, 2, 16);
    val += __shfl_down(val, 1, 16);
    if (sub == 0) u[node] = val;
}

__global__ void bin_count_k(const int* __restrict__ dst, int E, int chunk,
                            int nb, int* __restrict__ cnt) {
    __shared__ int hist[MAXNB];
    int e0 = blockIdx.x * chunk;
    int e1 = e0 + chunk; if (e1 > E) e1 = E;
    if (e0 >= E) return;
    for (int b = threadIdx.x; b < nb; b += blockDim.x) hist[b] = 0;
    __syncthreads();
    for (int i = e0 + (int)threadIdx.x * 4; i + 3 < e1; i += blockDim.x * 4) {
        int4 d = *reinterpret_cast<const int4*>(dst + i);
        atomicAdd(&hist[d.x >> RSHIFT], 1);
        atomicAdd(&hist[d.y >> RSHIFT], 1);
        atomicAdd(&hist[d.z >> RSHIFT], 1);
        atomicAdd(&hist[d.w >> RSHIFT], 1);
    }
    int rem = (e1 - e0) & 3;
    if ((int)threadIdx.x < rem) atomicAdd(&hist[dst[e1 - rem + threadIdx.x] >> RSHIFT], 1);
    __syncthreads();
    for (int b = threadIdx.x; b < nb; b += blockDim.x)
        if (hist[b]) atomicAdd(&cnt[b], hist[b]);
}

// parallel exclusive scan (4-aligned bucket bases) + cursors + out[g] = c0
// one block of 256 threads; nb <= 1024
__global__ void scan_init_k(const int* __restrict__ cnt, int nb,
                            int* __restrict__ base, int* __restrict__ cursor,
                            const float* __restrict__ sc, float* __restrict__ out, int G) {
    __shared__ int sums[256];
    int t = threadIdx.x;
    if (t < G) out[t] = sc[2];
    int v[4]; int s = 0;
    #pragma unroll
    for (int j = 0; j < 4; ++j) {
        int b = t * 4 + j;
        v[j] = (b < nb) ? ((cnt[b] + 3) & ~3) : 0;   // pad to 4 for uint4 reads
        s += v[j];
    }
    sums[t] = s;
    __syncthreads();
    for (int off = 1; off < 256; off <<= 1) {
        int xv = (t >= off) ? sums[t - off] : 0;
        __syncthreads();
        sums[t] += xv;
        __syncthreads();
    }
    int run = sums[t] - s;   // exclusive prefix
    #pragma unroll
    for (int j = 0; j < 4; ++j) {
        int b = t * 4 + j;
        if (b < nb) { base[b] = run; cursor[b] = run; }
        run += v[j];
    }
}

__global__ void bin_scatter_k(const int* __restrict__ src, const int* __restrict__ dst,
                              int E, int chunk, int nb,
                              int* __restrict__ cursor, unsigned int* __restrict__ binned) {
    __shared__ int hist[MAXNB];
    int e0 = blockIdx.x * chunk;
    int e1 = e0 + chunk; if (e1 > E) e1 = E;
    if (e0 >= E) return;
    for (int b = threadIdx.x; b < nb; b += blockDim.x) hist[b] = 0;
    __syncthreads();
    for (int i = e0 + (int)threadIdx.x * 4; i + 3 < e1; i += blockDim.x * 4) {
        int4 d = *reinterpret_cast<const int4*>(dst + i);
        atomicAdd(&hist[d.x >> RSHIFT], 1);
        atomicAdd(&hist[d.y >> RSHIFT], 1);
        atomicAdd(&hist[d.z >> RSHIFT], 1);
        atomicAdd(&hist[d.w >> RSHIFT], 1);
    }
    int rem = (e1 - e0) & 3;
    if ((int)threadIdx.x < rem) atomicAdd(&hist[dst[e1 - rem + threadIdx.x] >> RSHIFT], 1);
    __syncthreads();
    for (int b = threadIdx.x; b < nb; b += blockDim.x) {
        int c = hist[b];
        hist[b] = c ? atomicAdd(&cursor[b], c) : 0;
    }
    __syncthreads();
    for (int i = e0 + (int)threadIdx.x * 4; i + 3 < e1; i += blockDim.x * 4) {
        int4 s4 = *reinterpret_cast<const int4*>(src + i);
        int4 d4 = *reinterpret_cast<const int4*>(dst + i);
        int p;
        p = atomicAdd(&hist[d4.x >> RSHIFT], 1);
        binned[p] = (unsigned)s4.x | ((unsigned)(d4.x & (RNODES-1)) << 17);
        p = atomicAdd(&hist[d4.y >> RSHIFT], 1);
        binned[p] = (unsigned)s4.y | ((unsigned)(d4.y & (RNODES-1)) << 17);
        p = atomicAdd(&hist[d4.z >> RSHIFT], 1);
        binned[p] = (unsigned)s4.z | ((unsigned)(d4.z & (RNODES-1)) << 17);
        p = atomicAdd(&hist[d4.w >> RSHIFT], 1);
        binned[p] = (unsigned)s4.w | ((unsigned)(d4.w & (RNODES-1)) << 17);
    }
    if ((int)threadIdx.x < rem) {
        int i = e1 - rem + threadIdx.x;
        int s = src[i], d = dst[i];
        int p = atomicAdd(&hist[d >> RSHIFT], 1);
        binned[p] = (unsigned)s | ((unsigned)(d & (RNODES-1)) << 17);
    }
}

// in-degree per node -> dinv = rsqrt(deg+1); w = dinv * u
__global__ void degree_k(const unsigned int* __restrict__ binned, const int* __restrict__ base,
                         const int* __restrict__ endp, const float* __restrict__ u,
                         float* __restrict__ dinv, float* __restrict__ w, int n) {
    __shared__ int cnt[RNODES];
    int tid = threadIdx.x, b = blockIdx.x;
    if (tid < RNODES) cnt[tid] = 0;
    __syncthreads();
    int s0 = base[b], s1 = endp[b];
    int nvec = (s1 - s0) >> 2;
    for (int k = tid; k < nvec; k += blockDim.x) {
        uint4 p = *reinterpret_cast<const uint4*>(binned + s0 + 4 * k);
        atomicAdd(&cnt[p.x >> 17], 1);
        atomicAdd(&cnt[p.y >> 17], 1);
        atomicAdd(&cnt[p.z >> 17], 1);
        atomicAdd(&cnt[p.w >> 17], 1);
    }
    int i = s0 + 4 * nvec + tid;
    if (i < s1) atomicAdd(&cnt[binned[i] >> 17], 1);
    __syncthreads();
    int g = (b << RSHIFT) + tid;
    if (tid < RNODES && g < n) {
        float d = rsqrtf((float)(cnt[tid] + 1));
        dinv[g] = d;
        w[g] = d * u[g];
    }
}

// v = c1 + dinv*(sum of w[src]) + dinv^2*u ; wb = dinv*v
__global__ void conv_mid_k(const unsigned int* __restrict__ binned, const int* __restrict__ base,
                           const int* __restrict__ endp,
                           const float* __restrict__ w, const float* __restrict__ dinv,
                           const float* __restrict__ u, const float* __restrict__ sc,
                           float* __restrict__ v, float* __restrict__ wb, int n) {
    __shared__ float acc[RNODES];
    int tid = threadIdx.x, b = blockIdx.x;
    if (tid < RNODES) acc[tid] = 0.f;
    __syncthreads();
    int s0 = base[b], s1 = endp[b];
    int nvec = (s1 - s0) >> 2;
    for (int k = tid; k < nvec; k += blockDim.x) {
        uint4 p = *reinterpret_cast<const uint4*>(binned + s0 + 4 * k);
        float wx = w[p.x & 0x1FFFF];
        float wy = w[p.y & 0x1FFFF];
        float wz = w[p.z & 0x1FFFF];
        float ww = w[p.w & 0x1FFFF];
        atomicAdd(&acc[p.x >> 17], wx);
        atomicAdd(&acc[p.y >> 17], wy);
        atomicAdd(&acc[p.z >> 17], wz);
        atomicAdd(&acc[p.w >> 17], ww);
    }
    int i = s0 + 4 * nvec + tid;
    if (i < s1) { unsigned p = binned[i]; atomicAdd(&acc[p >> 17], w[p & 0x1FFFF]); }
    __syncthreads();
    int g = (b << RSHIFT) + tid;
    if (tid < RNODES && g < n) {
        float di = dinv[g];
        float val = sc[0] + di * acc[tid] + di * di * u[g];
        v[g] = val;
        wb[g] = di * val;
    }
}

// t = c2 + dinv*sum + dinv^2*v, then segmented pool by sorted batch id
__global__ void conv_final_k(const unsigned int* __restrict__ binned, const int* __restrict__ base,
                             const int* __restrict__ endp,
                             const float* __restrict__ wb, const float* __restrict__ dinv,
                             const float* __restrict__ v, const float* __restrict__ sc,
                             const int* __restrict__ batch, float* __restrict__ out, int n) {
    __shared__ float acc[RNODES];
    __shared__ float tbuf[RNODES];
    __shared__ int gbuf[RNODES];
    int tid = threadIdx.x, b = blockIdx.x;
    if (tid < RNODES) acc[tid] = 0.f;
    __syncthreads();
    int s0 = base[b], s1 = endp[b];
    int nvec = (s1 - s0) >> 2;
    for (int k = tid; k < nvec; k += blockDim.x) {
        uint4 p = *reinterpret_cast<const uint4*>(binned + s0 + 4 * k);
        float wx = wb[p.x & 0x1FFFF];
        float wy = wb[p.y & 0x1FFFF];
        float wz = wb[p.z & 0x1FFFF];
        float ww = wb[p.w & 0x1FFFF];
        atomicAdd(&acc[p.x >> 17], wx);
        atomicAdd(&acc[p.y >> 17], wy);
        atomicAdd(&acc[p.z >> 17], wz);
        atomicAdd(&acc[p.w >> 17], ww);
    }
    int i = s0 + 4 * nvec + tid;
    if (i < s1) { unsigned p = binned[i]; atomicAdd(&acc[p >> 17], wb[p & 0x1FFFF]); }
    __syncthreads();
    int g = (b << RSHIFT) + tid;
    float tval = 0.f; int gid = -1;
    if (tid < RNODES && g < n) {
        float di = dinv[g];
        tval = sc[1] + di * acc[tid] + di * di * v[g];
        gid = batch[g];
    }
    if (tid < RNODES) { tbuf[tid] = tval; gbuf[tid] = gid; }
    __syncthreads();
    if (tid < RNODES && g < n) {
        bool head = (tid == 0) || (gbuf[tid - 1] != gid);
        if (head) {
            float s = 0.f;
            int i2 = tid;
            while (i2 < RNODES && gbuf[i2] == gid) { s += tbuf[i2]; ++i2; }
            atomicAdd(&out[gid], s);
        }
    }
}

extern "C" void kernel_launch(void* const* d_in, const int* in_sizes, int n_in,
                              void* d_out, int out_size, void* d_ws, size_t ws_size,
                              hipStream_t stream)
{
    const float* x    = (const float*)d_in[0];
    const int*   ei   = (const int*)d_in[1];
    const int*   batch= (const int*)d_in[2];
    const float* W1   = (const float*)d_in[3];
    const float* b1   = (const float*)d_in[4];
    const float* W2   = (const float*)d_in[5];
    const float* b2   = (const float*)d_in[6];
    const float* Wf1  = (const float*)d_in[7];
    const float* bf1  = (const float*)d_in[8];
    const float* Wf2  = (const float*)d_in[9];
    const float* bf2  = (const float*)d_in[10];
    const float* Wf3  = (const float*)d_in[11];
    const float* bf3  = (const float*)d_in[12];
    const float* Wo   = (const float*)d_in[13];
    const float* bo   = (const float*)d_in[14];
    float* out = (float*)d_out;

    const int n = in_sizes[0] / 64;
    const int E = in_sizes[1] / 2;
    const int G = out_size;
    const int* src = ei;
    const int* dst = ei + E;
    const int nb = (n + RNODES - 1) >> RSHIFT;

    float* ws_f = (float*)d_ws;
    int*   ws_i = (int*)d_ws;
    float* w1c   = ws_f;                 // 64
    float* sc    = ws_f + 64;            // 3
    int*   cnt   = ws_i + 128;           // nb (<=1024)
    int*   basep = ws_i + 1280;          // nb
    int*   cursor= ws_i + 2432;          // nb -> becomes end pointers
    float* u     = ws_f + 3584;          // n
    float* dinv  = u + n;                // n
    float* w     = dinv + n;             // n  (dinv*u)
    float* v     = w + n;                // n
    float* wb    = v + n;                // n  (dinv*v)
    unsigned int* binned = (unsigned int*)(wb + n);  // E + 4*nb

    int chunk = (E + BINBLOCKS - 1) / BINBLOCKS;
    chunk = (chunk + 3) & ~3;

    hipLaunchKernelGGL(collapse_weights_k, dim3(1), dim3(64), 0, stream,
                       W1, b1, W2, b2, Wf1, bf1, Wf2, bf2, Wf3, bf3, Wo, bo,
                       w1c, sc, cnt, nb);
    hipLaunchKernelGGL(node_u_k, dim3((n / 4 * 64 + 255) / 256 + 1), dim3(256), 0, stream,
                       x, w1c, u, n);
    hipLaunchKernelGGL(bin_count_k, dim3(BINBLOCKS), dim3(BINTHREADS), 0, stream,
                       dst, E, chunk, nb, cnt);
    hipLaunchKernelGGL(scan_init_k, dim3(1), dim3(256), 0, stream,
                       cnt, nb, basep, cursor, sc, out, G);
    hipLaunchKernelGGL(bin_scatter_k, dim3(BINBLOCKS), dim3(BINTHREADS), 0, stream,
                       src, dst, E, chunk, nb, cursor, binned);
    hipLaunchKernelGGL(degree_k, dim3(nb), dim3(256), 0, stream,
                       binned, basep, cursor, u, dinv, w, n);
    hipLaunchKernelGGL(conv_mid_k, dim3(nb), dim3(256), 0, stream,
                       binned, basep, cursor, w, dinv, u, sc, v, wb, n);
    hipLaunchKernelGGL(conv_final_k, dim3(nb), dim3(256), 0, stream,
                       binned, basep, cursor, wb, dinv, v, sc, batch, out, n);
}

// Round 4
// 203.997 us; speedup vs baseline: 3.2984x; 1.0880x over previous
//
#include <hip/hip_runtime.h>

// GCN edge predictor, collapsed to scalar-per-node linear algebra:
//   u_i = x_i . w1c ;  v = A u + c1 ;  t = A v + c2 ;  out[g] = sum_g t + c0
//   A = D^-1/2 (Adj + I) D^-1/2
// R4: deterministic binning (no global atomics anywhere in binning):
//   bin_count: per-tile bucket hists (block-major, coalesced)
//   scanA/scanB: two-level exclusive scan -> per-(bucket,tile) global offsets
//   bin_scatter: block-local counting sort in LDS, dense flush to global

#define RSHIFT 7
#define RNODES 128           // nodes per bucket
#define NB_MAX 1024          // max buckets (n <= 131072; src fits 17 bits)
#define NBLK 512             // tiles for count/scatter
#define STHREADS 512
#define STAGE_CAP 8192       // max edges per tile (E <= NBLK*STAGE_CAP)

__global__ void collapse_weights_k(
    const float* __restrict__ W1, const float* __restrict__ b1,
    const float* __restrict__ W2, const float* __restrict__ b2,
    const float* __restrict__ Wf1, const float* __restrict__ bf1,
    const float* __restrict__ Wf2, const float* __restrict__ bf2,
    const float* __restrict__ Wf3, const float* __restrict__ bf3,
    const float* __restrict__ Wo, const float* __restrict__ bo,
    float* __restrict__ w1c, float* __restrict__ sc)
{
    __shared__ float wo[10], w3[20], w2[30], w1[50], w2c[60];
    const int t = threadIdx.x;  // 64 threads
    if (t < 10) wo[t] = Wo[t];
    __syncthreads();
    if (t < 20) { float s = 0.f; for (int j = 0; j < 10; ++j) s += Wf3[t*10+j]*wo[j]; w3[t] = s; }
    __syncthreads();
    if (t < 30) { float s = 0.f; for (int j = 0; j < 20; ++j) s += Wf2[t*20+j]*w3[j]; w2[t] = s; }
    __syncthreads();
    if (t < 50) { float s = 0.f; for (int j = 0; j < 30; ++j) s += Wf1[t*30+j]*w2[j]; w1[t] = s; }
    __syncthreads();
    if (t < 60) { float s = 0.f; for (int j = 0; j < 50; ++j) s += W2[t*50+j]*w1[j]; w2c[t] = s; }
    __syncthreads();
    { float s = 0.f; for (int j = 0; j < 60; ++j) s += W1[t*60+j]*w2c[j]; w1c[t] = s; }
    if (t == 0) {
        float c1 = 0.f; for (int j = 0; j < 60; ++j) c1 += b1[j]*w2c[j];
        float c2 = 0.f; for (int j = 0; j < 50; ++j) c2 += b2[j]*w1[j];
        float c0 = bo[0];
        for (int j = 0; j < 30; ++j) c0 += bf1[j]*w2[j];
        for (int j = 0; j < 20; ++j) c0 += bf2[j]*w3[j];
        for (int j = 0; j < 10; ++j) c0 += bf3[j]*wo[j];
        sc[0] = c1; sc[1] = c2; sc[2] = c0;
    }
}

// 4 nodes per wave, float4 per 16-lane group: u[i] = x[i,:] . w1c
__global__ void node_u_k(const float* __restrict__ x, const float* __restrict__ w1c,
                         float* __restrict__ u, int n) {
    int tid = blockIdx.x * blockDim.x + threadIdx.x;
    int wave = tid >> 6;
    int lane = threadIdx.x & 63;
    int node = wave * 4 + (lane >> 4);
    int sub = lane & 15;
    if (node >= n) return;
    float4 xv = *reinterpret_cast<const float4*>(x + (size_t)node * 64 + sub * 4);
    float4 wv = *reinterpret_cast<const float4*>(w1c + sub * 4);
    float val = xv.x * wv.x + xv.y * wv.y + xv.z * wv.z + xv.w * wv.w;
    val += __shfl_down(val, 8, 16);
    val += __shfl_down(val, 4, 16);
    val += __shfl_down(val, 2, 16);
    val += __shfl_down(val, 1, 16);
    if (sub == 0) u[node] = val;
}

// per-tile bucket histogram -> cnt_bm[tile*nb + b]  (coalesced write)
__global__ void bin_count_k(const int* __restrict__ dst, int E, int chunk,
                            int nb, int* __restrict__ cnt_bm) {
    __shared__ int hist[NB_MAX];
    int tid = threadIdx.x;
    hist[tid] = 0; hist[tid + 512] = 0;
    __syncthreads();
    int e0 = blockIdx.x * chunk;
    int e1 = e0 + chunk; if (e1 > E) e1 = E;
    for (int j = 0; j < STAGE_CAP / (STHREADS * 4); ++j) {
        int i = e0 + tid * 4 + j * (STHREADS * 4);
        if (i + 3 < e1) {
            int4 d = *reinterpret_cast<const int4*>(dst + i);
            atomicAdd(&hist[d.x >> RSHIFT], 1);
            atomicAdd(&hist[d.y >> RSHIFT], 1);
            atomicAdd(&hist[d.z >> RSHIFT], 1);
            atomicAdd(&hist[d.w >> RSHIFT], 1);
        } else if (i < e1) {
            for (int k = i; k < e1; ++k) atomicAdd(&hist[dst[k] >> RSHIFT], 1);
        }
    }
    __syncthreads();
    for (int b = tid; b < nb; b += STHREADS)
        cnt_bm[(size_t)blockIdx.x * nb + b] = hist[b];
}

// one block per bucket: exclusive scan over tiles -> offs[b*NBLK + k], total[b]
__global__ void scanA_k(const int* __restrict__ cnt_bm, int nb,
                        int* __restrict__ offs, int* __restrict__ total) {
    __shared__ int sums[STHREADS];
    int k = threadIdx.x, b = blockIdx.x;
    int v = cnt_bm[(size_t)k * nb + b];
    sums[k] = v;
    __syncthreads();
    for (int off = 1; off < STHREADS; off <<= 1) {
        int a = (k >= off) ? sums[k - off] : 0;
        __syncthreads();
        sums[k] += a;
        __syncthreads();
    }
    offs[(size_t)b * NBLK + k] = sums[k] - v;
    if (k == STHREADS - 1) total[b] = sums[k];
}

// scan bucket totals (4-aligned bases) -> base[b], endp[b]; also out[g] = c0
__global__ void scanB_k(const int* __restrict__ total, int nb,
                        int* __restrict__ base, int* __restrict__ endp,
                        const float* __restrict__ sc, float* __restrict__ out, int G) {
    __shared__ int sums[STHREADS];
    int t = threadIdx.x;
    if (t < G) out[t] = sc[2];
    int b0 = 2 * t, b1 = 2 * t + 1;
    int t0 = (b0 < nb) ? total[b0] : 0;
    int t1 = (b1 < nb) ? total[b1] : 0;
    int a0 = (t0 + 3) & ~3, a1 = (t1 + 3) & ~3;
    int pair = a0 + a1;
    sums[t] = pair;
    __syncthreads();
    for (int off = 1; off < STHREADS; off <<= 1) {
        int a = (t >= off) ? sums[t - off] : 0;
        __syncthreads();
        sums[t] += a;
        __syncthreads();
    }
    int excl = sums[t] - pair;
    if (b0 < nb) { base[b0] = excl; endp[b0] = excl + t0; }
    if (b1 < nb) { base[b1] = excl + a0; endp[b1] = excl + a0 + t1; }
}

// block-local counting sort of a tile, dense flush to bucket-contiguous global
__global__ void bin_scatter_k(const int* __restrict__ src, const int* __restrict__ dst,
                              int E, int chunk, int nb,
                              const int* __restrict__ base, const int* __restrict__ offs,
                              unsigned int* __restrict__ binned) {
    __shared__ int hist[NB_MAX];
    __shared__ int tbase[NB_MAX];
    __shared__ int adj[NB_MAX];
    __shared__ int sums[STHREADS];
    __shared__ unsigned int staged[STAGE_CAP];
    __shared__ unsigned short bof[STAGE_CAP];
    const int tid = threadIdx.x;
    hist[tid] = 0; hist[tid + 512] = 0;
    __syncthreads();
    int e0 = blockIdx.x * chunk;
    int e1 = e0 + chunk; if (e1 > E) e1 = E;
    const int QMAX = STAGE_CAP / (STHREADS * 4);   // 4 quads -> 16 edges/thread
    unsigned int pk[QMAX * 4];
    int bk[QMAX * 4];
    int rk[QMAX * 4];
    int nv[QMAX];
    #pragma unroll
    for (int j = 0; j < QMAX; ++j) {
        int i = e0 + tid * 4 + j * (STHREADS * 4);
        int cnt = e1 - i; if (cnt > 4) cnt = 4; if (cnt < 0) cnt = 0;
        nv[j] = cnt;
        if (cnt == 4) {
            int4 s4 = *reinterpret_cast<const int4*>(src + i);
            int4 d4 = *reinterpret_cast<const int4*>(dst + i);
            pk[j*4+0] = (unsigned)s4.x | ((unsigned)(d4.x & (RNODES-1)) << 17);
            pk[j*4+1] = (unsigned)s4.y | ((unsigned)(d4.y & (RNODES-1)) << 17);
            pk[j*4+2] = (unsigned)s4.z | ((unsigned)(d4.z & (RNODES-1)) << 17);
            pk[j*4+3] = (unsigned)s4.w | ((unsigned)(d4.w & (RNODES-1)) << 17);
            bk[j*4+0] = d4.x >> RSHIFT; bk[j*4+1] = d4.y >> RSHIFT;
            bk[j*4+2] = d4.z >> RSHIFT; bk[j*4+3] = d4.w >> RSHIFT;
            rk[j*4+0] = atomicAdd(&hist[bk[j*4+0]], 1);
            rk[j*4+1] = atomicAdd(&hist[bk[j*4+1]], 1);
            rk[j*4+2] = atomicAdd(&hist[bk[j*4+2]], 1);
            rk[j*4+3] = atomicAdd(&hist[bk[j*4+3]], 1);
        } else {
            for (int l = 0; l < cnt; ++l) {
                int s = src[i + l], d = dst[i + l];
                pk[j*4+l] = (unsigned)s | ((unsigned)(d & (RNODES-1)) << 17);
                bk[j*4+l] = d >> RSHIFT;
                rk[j*4+l] = atomicAdd(&hist[bk[j*4+l]], 1);
            }
        }
    }
    __syncthreads();
    // block-exclusive scan of hist[0..1023] (2 slots per thread)
    int h0 = hist[2*tid], h1 = hist[2*tid+1];
    int pair = h0 + h1;
    sums[tid] = pair;
    __syncthreads();
    for (int off = 1; off < STHREADS; off <<= 1) {
        int a = (tid >= off) ? sums[tid - off] : 0;
        __syncthreads();
        sums[tid] += a;
        __syncthreads();
    }
    int excl = sums[tid] - pair;
    tbase[2*tid] = excl;
    tbase[2*tid+1] = excl + h0;
    // adj[b]: LDS slot -> global slot adjustment for this tile
    for (int b = 2*tid; b <= 2*tid+1; ++b)
        if (b < nb) adj[b] = base[b] + offs[(size_t)b * NBLK + blockIdx.x] - tbase[b];
    __syncthreads();
    // write bucket-sorted into LDS
    #pragma unroll
    for (int j = 0; j < QMAX; ++j) {
        for (int l = 0; l < nv[j]; ++l) {
            int b = bk[j*4+l];
            int slot = tbase[b] + rk[j*4+l];
            staged[slot] = pk[j*4+l];
            bof[slot] = (unsigned short)b;
        }
    }
    __syncthreads();
    // dense flush
    int tcount = e1 - e0;
    for (int s = tid; s < tcount; s += STHREADS) {
        int b = bof[s];
        binned[adj[b] + s] = staged[s];
    }
}

// in-degree per node -> dinv = rsqrt(deg+1); w = dinv * u
__global__ void degree_k(const unsigned int* __restrict__ binned, const int* __restrict__ base,
                         const int* __restrict__ endp, const float* __restrict__ u,
                         float* __restrict__ dinv, float* __restrict__ w, int n) {
    __shared__ int cnt[RNODES];
    int tid = threadIdx.x, b = blockIdx.x;
    if (tid < RNODES) cnt[tid] = 0;
    __syncthreads();
    int s0 = base[b], s1 = endp[b];
    int nvec = (s1 - s0) >> 2;
    for (int k = tid; k < nvec; k += blockDim.x) {
        uint4 p = *reinterpret_cast<const uint4*>(binned + s0 + 4 * k);
        atomicAdd(&cnt[p.x >> 17], 1);
        atomicAdd(&cnt[p.y >> 17], 1);
        atomicAdd(&cnt[p.z >> 17], 1);
        atomicAdd(&cnt[p.w >> 17], 1);
    }
    int i = s0 + 4 * nvec + tid;
    if (i < s1) atomicAdd(&cnt[binned[i] >> 17], 1);
    __syncthreads();
    int g = (b << RSHIFT) + tid;
    if (tid < RNODES && g < n) {
        float d = rsqrtf((float)(cnt[tid] + 1));
        dinv[g] = d;
        w[g] = d * u[g];
    }
}

// v = c1 + dinv*(sum of w[src]) + dinv^2*u ; wb = dinv*v
__global__ void conv_mid_k(const unsigned int* __restrict__ binned, const int* __restrict__ base,
                           const int* __restrict__ endp,
                           const float* __restrict__ w, const float* __restrict__ dinv,
                           const float* __restrict__ u, const float* __restrict__ sc,
                           float* __restrict__ v, float* __restrict__ wb, int n) {
    __shared__ float acc[RNODES];
    int tid = threadIdx.x, b = blockIdx.x;
    if (tid < RNODES) acc[tid] = 0.f;
    __syncthreads();
    int s0 = base[b], s1 = endp[b];
    int nvec = (s1 - s0) >> 2;
    for (int k = tid; k < nvec; k += blockDim.x) {
        uint4 p = *reinterpret_cast<const uint4*>(binned + s0 + 4 * k);
        float wx = w[p.x & 0x1FFFF];
        float wy = w[p.y & 0x1FFFF];
        float wz = w[p.z & 0x1FFFF];
        float ww = w[p.w & 0x1FFFF];
        atomicAdd(&acc[p.x >> 17], wx);
        atomicAdd(&acc[p.y >> 17], wy);
        atomicAdd(&acc[p.z >> 17], wz);
        atomicAdd(&acc[p.w >> 17], ww);
    }
    int i = s0 + 4 * nvec + tid;
    if (i < s1) { unsigned p = binned[i]; atomicAdd(&acc[p >> 17], w[p & 0x1FFFF]); }
    __syncthreads();
    int g = (b << RSHIFT) + tid;
    if (tid < RNODES && g < n) {
        float di = dinv[g];
        float val = sc[0] + di * acc[tid] + di * di * u[g];
        v[g] = val;
        wb[g] = di * val;
    }
}

// t = c2 + dinv*sum + dinv^2*v, then segmented pool by sorted batch id
__global__ void conv_final_k(const unsigned int* __restrict__ binned, const int* __restrict__ base,
                             const int* __restrict__ endp,
                             const float* __restrict__ wb, const float* __restrict__ dinv,
                             const float* __restrict__ v, const float* __restrict__ sc,
                             const int* __restrict__ batch, float* __restrict__ out, int n) {
    __shared__ float acc[RNODES];
    __shared__ float tbuf[RNODES];
    __shared__ int gbuf[RNODES];
    int tid = threadIdx.x, b = blockIdx.x;
    if (tid < RNODES) acc[tid] = 0.f;
    __syncthreads();
    int s0 = base[b], s1 = endp[b];
    int nvec = (s1 - s0) >> 2;
    for (int k = tid; k < nvec; k += blockDim.x) {
        uint4 p = *reinterpret_cast<const uint4*>(binned + s0 + 4 * k);
        float wx = wb[p.x & 0x1FFFF];
        float wy = wb[p.y & 0x1FFFF];
        float wz = wb[p.z & 0x1FFFF];
        float ww = wb[p.w & 0x1FFFF];
        atomicAdd(&acc[p.x >> 17], wx);
        atomicAdd(&acc[p.y >> 17], wy);
        atomicAdd(&acc[p.z >> 17], wz);
        atomicAdd(&acc[p.w >> 17], ww);
    }
    int i = s0 + 4 * nvec + tid;
    if (i < s1) { unsigned p = binned[i]; atomicAdd(&acc[p >> 17], wb[p & 0x1FFFF]); }
    __syncthreads();
    int g = (b << RSHIFT) + tid;
    float tval = 0.f; int gid = -1;
    if (tid < RNODES && g < n) {
        float di = dinv[g];
        tval = sc[1] + di * acc[tid] + di * di * v[g];
        gid = batch[g];
    }
    if (tid < RNODES) { tbuf[tid] = tval; gbuf[tid] = gid; }
    __syncthreads();
    if (tid < RNODES && g < n) {
        bool head = (tid == 0) || (gbuf[tid - 1] != gid);
        if (head) {
            float s = 0.f;
            int i2 = tid;
            while (i2 < RNODES && gbuf[i2] == gid) { s += tbuf[i2]; ++i2; }
            atomicAdd(&out[gid], s);
        }
    }
}

extern "C" void kernel_launch(void* const* d_in, const int* in_sizes, int n_in,
                              void* d_out, int out_size, void* d_ws, size_t ws_size,
                              hipStream_t stream)
{
    const float* x    = (const float*)d_in[0];
    const int*   ei   = (const int*)d_in[1];
    const int*   batch= (const int*)d_in[2];
    const float* W1   = (const float*)d_in[3];
    const float* b1   = (const float*)d_in[4];
    const float* W2   = (const float*)d_in[5];
    const float* b2   = (const float*)d_in[6];
    const float* Wf1  = (const float*)d_in[7];
    const float* bf1  = (const float*)d_in[8];
    const float* Wf2  = (const float*)d_in[9];
    const float* bf2  = (const float*)d_in[10];
    const float* Wf3  = (const float*)d_in[11];
    const float* bf3  = (const float*)d_in[12];
    const float* Wo   = (const float*)d_in[13];
    const float* bo   = (const float*)d_in[14];
    float* out = (float*)d_out;

    const int n = in_sizes[0] / 64;
    const int E = in_sizes[1] / 2;
    const int G = out_size;
    const int* src = ei;
    const int* dst = ei + E;
    const int nb = (n + RNODES - 1) >> RSHIFT;

    // workspace layout (element offsets, all 16B-aligned blocks)
    float* ws_f = (float*)d_ws;
    int*   ws_i = (int*)d_ws;
    float* w1c    = ws_f;                    // 64
    float* sc     = ws_f + 64;               // 3 (+pad to 128)
    int*   basep  = ws_i + 128;              // NB_MAX
    int*   endp   = ws_i + 128 + NB_MAX;     // NB_MAX
    int*   total  = ws_i + 128 + 2*NB_MAX;   // NB_MAX
    int*   offs   = ws_i + 128 + 3*NB_MAX;   // nb*NBLK (<= NB_MAX*NBLK? use nb*NBLK)
    size_t off_u  = 128 + 3*(size_t)NB_MAX + (size_t)nb * NBLK;
    off_u = (off_u + 3) & ~(size_t)3;
    float* u      = ws_f + off_u;            // n
    float* dinv   = u + n;                   // n
    float* w      = dinv + n;                // n
    float* v      = w + n;                   // n
    float* wb     = v + n;                   // n
    size_t off_b  = off_u + 5*(size_t)n;
    off_b = (off_b + 3) & ~(size_t)3;
    unsigned int* binned = (unsigned int*)(ws_f + off_b);   // E + 4*nb
    int* cnt_bm = (int*)binned;              // aliased: used only before scatter writes binned

    int chunk = (E + NBLK - 1) / NBLK;
    chunk = (chunk + 3) & ~3;

    hipLaunchKernelGGL(collapse_weights_k, dim3(1), dim3(64), 0, stream,
                       W1, b1, W2, b2, Wf1, bf1, Wf2, bf2, Wf3, bf3, Wo, bo, w1c, sc);
    hipLaunchKernelGGL(node_u_k, dim3((n / 4 * 64 + 255) / 256 + 1), dim3(256), 0, stream,
                       x, w1c, u, n);
    hipLaunchKernelGGL(bin_count_k, dim3(NBLK), dim3(STHREADS), 0, stream,
                       dst, E, chunk, nb, cnt_bm);
    hipLaunchKernelGGL(scanA_k, dim3(nb), dim3(STHREADS), 0, stream,
                       cnt_bm, nb, offs, total);
    hipLaunchKernelGGL(scanB_k, dim3(1), dim3(STHREADS), 0, stream,
                       total, nb, basep, endp, sc, out, G);
    hipLaunchKernelGGL(bin_scatter_k, dim3(NBLK), dim3(STHREADS), 0, stream,
                       src, dst, E, chunk, nb, basep, offs, binned);
    hipLaunchKernelGGL(degree_k, dim3(nb), dim3(512), 0, stream,
                       binned, basep, endp, u, dinv, w, n);
    hipLaunchKernelGGL(conv_mid_k, dim3(nb), dim3(512), 0, stream,
                       binned, basep, endp, w, dinv, u, sc, v, wb, n);
    hipLaunchKernelGGL(conv_final_k, dim3(nb), dim3(512), 0, stream,
                       binned, basep, endp, wb, dinv, v, sc, batch, out, n);
}